// Round 17
// baseline (391.583 us; speedup 1.0000x reference)
//
#include <hip/hip_runtime.h>
#include <hip/hip_fp16.h>
#include <hip/hip_cooperative_groups.h>

namespace cg = cooperative_groups;

#define N_NODES 50000
#define N_EDGES 800000
#define DIM 64
#define N_GRAPH 512
#define N_CLASS 10
#define NTILES (N_NODES / 16)                 // 3125 MFMA row-tiles
#define TPB ((NTILES + 1) / 2)                // 1563 tile-pairs per branch
#define BUCK 128                              // nodes per bucket
#define NBUCK ((N_NODES + BUCK - 1) / BUCK)   // 391
#define CAP 4096                              // edge capacity per bucket
#define NBA 128                               // bucket chunks per branch
#define EPA (N_EDGES / NBA)                   // 6250 edges per chunk
#define RSTRIDE (BUCK + 1)                    // 129
#define APAD 72                               // As16 row stride (halves): 144B = 9x16B
#define CURPAD 16                             // cursor padding: 1 counter per 64B line

typedef _Float16 f16;
typedef f16 f16x8 __attribute__((ext_vector_type(8)));
typedef float f32x4 __attribute__((ext_vector_type(4)));

struct MegaArgs {
    const int *src_sc, *dst_sc, *src_fc, *dst_fc;
    unsigned int *pairs_sc, *pairs_fc;
    int* cursor;
    const float* x;
    f16* xh;
    const float *W0, *W1;
    f16* wfrag;
    unsigned short *sorted_sc, *sorted_fc;
    int *rowg_sc, *rowg_fc;
    const float *b0, *b1;
    f16 *Hs, *Hf, *Gs, *Gf;
    const float *Wout, *bout;
    const int* batch;
    float* out;
};

struct SmP0 { int hist[NBUCK]; int cbase[NBUCK]; int cnt2[NBUCK]; };
struct SmP1 { unsigned short slo[CAP]; int row[BUCK + 1]; int cur[BUCK]; };
struct SmP2 { f16 As16[2][16][APAD]; };
struct SmP4 { int bounds[2]; float hs[8][DIM]; };
union SmAll { SmP0 p0; SmP1 p1; SmP2 p2; SmP4 p4; };

// ---------------- layer unit: gather-aggregate + MFMA for a tile pair ----------------
__device__ __forceinline__ void layer_unit(const MegaArgs& a, SmAll& sm, int u, int layer) {
    int br = u & 1, pair = u >> 1;
    const unsigned short* sortedp = br ? a.sorted_fc : a.sorted_sc;
    const int* rowg = br ? a.rowg_fc : a.rowg_sc;
    const f16* in; f16* outp; const float* bias; const f16* wf;
    if (layer == 0) {
        in = a.xh; outp = br ? a.Hf : a.Hs;
        wf = a.wfrag + (br ? 2 : 0) * 4096; bias = br ? a.b1 : a.b0;
    } else {
        in = br ? a.Hf : a.Hs; outp = br ? a.Gf : a.Gs;
        wf = a.wfrag + (br ? 3 : 1) * 4096; bias = (br ? a.b1 : a.b0) + DIM;
    }
    int t = threadIdx.x, w = t >> 6, lane = t & 63;
    int tp = w >> 2, w4 = w & 3;
    int tile = pair * 2 + tp;
    bool active = (tile < NTILES);
    int nbase = tile * 16;
    int q = nbase >> 7;
    const unsigned short* slo = sortedp + (size_t)q * CAP;
    const int* rr = rowg + q * RSTRIDE;
    int eg = lane >> 3, c8 = (lane & 7) << 3;

    if (active) {
#pragma unroll
        for (int i = 0; i < 4; ++i) {
            int nl = w4 * 4 + i;
            int dl = (nbase & (BUCK - 1)) + nl;
            int beg = rr[dl], end = rr[dl + 1];
            float iv = 1.0f / fmaxf((float)(end - beg), 1.0f);
            float acc[8] = {0.f, 0.f, 0.f, 0.f, 0.f, 0.f, 0.f, 0.f};
            int k = beg;
            for (; k + 16 <= end; k += 16) {
                int s0 = slo[k + eg];
                int s1 = slo[k + 8 + eg];
                f16x8 v0 = *(const f16x8*)(in + (size_t)s0 * DIM + c8);
                f16x8 v1 = *(const f16x8*)(in + (size_t)s1 * DIM + c8);
#pragma unroll
                for (int m = 0; m < 8; ++m) acc[m] += (float)v0[m] + (float)v1[m];
            }
            if (k + 8 <= end) {
                f16x8 v0 = *(const f16x8*)(in + (size_t)slo[k + eg] * DIM + c8);
#pragma unroll
                for (int m = 0; m < 8; ++m) acc[m] += (float)v0[m];
                k += 8;
            }
            if (k + eg < end) {
                f16x8 v0 = *(const f16x8*)(in + (size_t)slo[k + eg] * DIM + c8);
#pragma unroll
                for (int m = 0; m < 8; ++m) acc[m] += (float)v0[m];
            }
#pragma unroll
            for (int m = 0; m < 8; ++m) {
                acc[m] += __shfl_xor(acc[m], 8, 64);
                acc[m] += __shfl_xor(acc[m], 16, 64);
                acc[m] += __shfl_xor(acc[m], 32, 64);
            }
            if (eg == 0) {
                f16x8 r;
#pragma unroll
                for (int m = 0; m < 8; ++m) r[m] = (f16)(acc[m] * iv);
                *(f16x8*)&sm.p2.As16[tp][nl][c8] = r;
            }
        }
    }
    __syncthreads();
    if (active) {
        int g = lane >> 4, c = lane & 15;
        f16x8 a0 = *(const f16x8*)&sm.p2.As16[tp][c][8 * g];
        f16x8 a1 = *(const f16x8*)&sm.p2.As16[tp][c][32 + 8 * g];
        f16x8 b0 = *(const f16x8*)(wf + ((w4 * 2 + 0) * 64 + lane) * 8);
        f16x8 b1 = *(const f16x8*)(wf + ((w4 * 2 + 1) * 64 + lane) * 8);
        f32x4 acc = {0.f, 0.f, 0.f, 0.f};
        acc = __builtin_amdgcn_mfma_f32_16x16x32_f16(a0, b0, acc, 0, 0, 0);
        acc = __builtin_amdgcn_mfma_f32_16x16x32_f16(a1, b1, acc, 0, 0, 0);
        float bs = bias[w4 * 16 + c];
#pragma unroll
        for (int i = 0; i < 4; ++i) {
            float v = fmaxf(acc[i] + bs, 0.0f);
            outp[((size_t)nbase + 4 * g + i) * DIM + w4 * 16 + c] = (f16)v;
        }
    }
    __syncthreads();
}

// ---------------- the whole pipeline as one cooperative kernel ----------------
__global__ void __launch_bounds__(512, 4)
mega_kernel(MegaArgs a) {
    cg::grid_group grid = cg::this_grid();
    __shared__ SmAll sm;
    const int t = threadIdx.x;
    const int bid = blockIdx.x;
    const int nb = gridDim.x;

    // ===== P0: x->fp16 conv + W fragments + coarse bucket scatter =====
    {
        int gtid = bid * 512 + t, gstride = nb * 512;
        for (int i = gtid; i < N_NODES * DIM / 4; i += gstride) {
            float4 v = *(const float4*)(a.x + (size_t)i * 4);
            union { __half2 h2[2]; float2 f2; } u;
            u.h2[0] = __floats2half2_rn(v.x, v.y);
            u.h2[1] = __floats2half2_rn(v.z, v.w);
            *(float2*)((__half*)a.xh + (size_t)i * 4) = u.f2;
        }
        for (int i = gtid; i < 4 * 4096; i += gstride) {
            int mat = i >> 12, idx = i & 4095;
            const float* W = (mat & 2) ? a.W1 : a.W0;
            if (mat & 1) W += DIM * DIM;
            int ct = idx >> 10, kk = (idx >> 9) & 1, l = (idx >> 3) & 63, ii = idx & 7;
            int k = kk * 32 + (l >> 4) * 8 + ii;
            int col = ct * 16 + (l & 15);
            a.wfrag[mat * 4096 + idx] = (f16)W[k * DIM + col];
        }
        for (int vb = bid; vb < 2 * NBA; vb += nb) {
            int br = vb >> 7;
            int chunk = vb & (NBA - 1);
            const int* src = br ? a.src_fc : a.src_sc;
            const int* dst = br ? a.dst_fc : a.dst_sc;
            unsigned int* pairs = br ? a.pairs_fc : a.pairs_sc;
            int* cur = a.cursor + br * NBUCK * CURPAD;
            for (int i = t; i < NBUCK; i += 512) { sm.p0.hist[i] = 0; sm.p0.cnt2[i] = 0; }
            __syncthreads();
            int lo = chunk * EPA, hi = lo + EPA;
            for (int e = lo + t; e < hi; e += 512)
                atomicAdd(&sm.p0.hist[dst[e] >> 7], 1);
            __syncthreads();
            for (int i = t; i < NBUCK; i += 512)
                sm.p0.cbase[i] = sm.p0.hist[i] ? atomicAdd(&cur[i * CURPAD], sm.p0.hist[i]) : 0;
            __syncthreads();
            for (int e = lo + t; e < hi; e += 512) {
                int d = dst[e];
                int q = d >> 7;
                int idx = atomicAdd(&sm.p0.cnt2[q], 1) + sm.p0.cbase[q];
                if (idx < CAP)
                    pairs[(size_t)q * CAP + idx] =
                        (unsigned int)src[e] | ((unsigned int)(d & (BUCK - 1)) << 16);
            }
            __syncthreads();
        }
    }
    grid.sync();

    // ===== P1: per-bucket LDS counting sort -> sorted lists + row offsets =====
    for (int u = bid; u < 2 * NBUCK; u += nb) {
        int br = (u >= NBUCK);
        int q = br ? u - NBUCK : u;
        const unsigned int* pq = (br ? a.pairs_fc : a.pairs_sc) + (size_t)q * CAP;
        unsigned short* sorted = br ? a.sorted_fc : a.sorted_sc;
        int* rowg = br ? a.rowg_fc : a.rowg_sc;
        int cnt = a.cursor[(br * NBUCK + q) * CURPAD];
        if (cnt > CAP) cnt = CAP;
        for (int i = t; i < BUCK; i += 512) { sm.p1.row[i + 1] = 0; sm.p1.cur[i] = 0; }
        if (t == 0) sm.p1.row[0] = 0;
        __syncthreads();
        for (int e = t; e < cnt; e += 512)
            atomicAdd(&sm.p1.row[(pq[e] >> 16) + 1], 1);
        __syncthreads();
        for (int off = 1; off < BUCK; off <<= 1) {
            int v = 0;
            if (t < BUCK && (t + 1) - off >= 1) v = sm.p1.row[t + 1 - off];
            __syncthreads();
            if (t < BUCK) sm.p1.row[t + 1] += v;
            __syncthreads();
        }
        for (int e = t; e < cnt; e += 512) {
            unsigned int u2 = pq[e];
            int dl = u2 >> 16;
            int pos = sm.p1.row[dl] + atomicAdd(&sm.p1.cur[dl], 1);
            sm.p1.slo[pos] = (unsigned short)(u2 & 0xffffu);
        }
        __syncthreads();
        for (int i = t; i <= BUCK; i += 512) rowg[q * RSTRIDE + i] = sm.p1.row[i];
        unsigned int* so = (unsigned int*)(sorted + (size_t)q * CAP);
        const unsigned int* sl2 = (const unsigned int*)sm.p1.slo;
        for (int i = t; i < (cnt + 1) / 2; i += 512) so[i] = sl2[i];
        __syncthreads();
    }
    grid.sync();

    // ===== P2: layer 0 =====
    for (int u = bid; u < 2 * TPB; u += nb) layer_unit(a, sm, u, 0);
    grid.sync();

    // ===== P3: layer 1 =====
    for (int u = bid; u < 2 * TPB; u += nb) layer_unit(a, sm, u, 1);
    grid.sync();

    // ===== P4: per-graph projection =====
    for (int g = bid; g < N_GRAPH; g += nb) {
        if (t < 2) {
            int target = g + t;
            int lo = 0, hi = N_NODES;
            while (lo < hi) { int mid = (lo + hi) >> 1; if (a.batch[mid] < target) lo = mid + 1; else hi = mid; }
            sm.p4.bounds[t] = lo;
        }
        __syncthreads();
        int beg = sm.p4.bounds[0], end = sm.p4.bounds[1];
        int w = t >> 6, j = t & 63;
        float s = 0.0f;
        for (int n = beg + w; n < end; n += 8)
            s += (float)a.Gs[(size_t)n * DIM + j] + (float)a.Gf[(size_t)n * DIM + j];
        sm.p4.hs[w][j] = s;
        __syncthreads();
        if (t < DIM) {
            float v = 0.0f;
#pragma unroll
            for (int ww = 0; ww < 8; ++ww) v += sm.p4.hs[ww][t];
            sm.p4.hs[0][t] = v * 0.5f;
        }
        __syncthreads();
        if (t < N_CLASS) {
            int cntn = end - beg;
            float accv = 0.0f;
#pragma unroll
            for (int d = 0; d < DIM; ++d) accv += sm.p4.hs[0][d] * a.Wout[d * N_CLASS + t];
            a.out[g * N_CLASS + t] = (cntn > 0) ? (accv / (float)cntn + a.bout[t]) : 0.0f;
        }
        __syncthreads();
    }
}

extern "C" void kernel_launch(void* const* d_in, const int* in_sizes, int n_in,
                              void* d_out, int out_size, void* d_ws, size_t ws_size,
                              hipStream_t stream) {
    const float* x    = (const float*)d_in[0];
    const float* W0   = (const float*)d_in[1];
    const float* b0   = (const float*)d_in[2];
    const float* W1   = (const float*)d_in[3];
    const float* b1   = (const float*)d_in[4];
    const float* Wout = (const float*)d_in[5];
    const float* bout = (const float*)d_in[6];
    const int* ei_sc  = (const int*)d_in[7];
    const int* ei_fc  = (const int*)d_in[8];
    const int* batch  = (const int*)d_in[9];

    // ---- workspace layout (byte-based) ----
    char* ws = (char*)d_ws;
    size_t off = 0;
    auto alloc = [&](size_t bytes) { void* p = ws + off; off += (bytes + 15) & ~size_t(15); return p; };
    f16* xh   = (f16*)alloc((size_t)N_NODES * DIM * 2);
    f16* Hs_  = (f16*)alloc((size_t)N_NODES * DIM * 2);
    f16* Hf_  = (f16*)alloc((size_t)N_NODES * DIM * 2);
    f16* Gs_  = (f16*)alloc((size_t)N_NODES * DIM * 2);
    f16* Gf_  = (f16*)alloc((size_t)N_NODES * DIM * 2);
    f16* wfrag = (f16*)alloc(4 * 4096 * 2);
    unsigned int* pairs_sc = (unsigned int*)alloc((size_t)NBUCK * CAP * 4);
    unsigned int* pairs_fc = (unsigned int*)alloc((size_t)NBUCK * CAP * 4);
    unsigned short* sorted_sc = (unsigned short*)alloc((size_t)NBUCK * CAP * 2);
    unsigned short* sorted_fc = (unsigned short*)alloc((size_t)NBUCK * CAP * 2);
    int* rowg_sc = (int*)alloc((size_t)NBUCK * RSTRIDE * 4);
    int* rowg_fc = (int*)alloc((size_t)NBUCK * RSTRIDE * 4);
    int* cursor  = (int*)alloc((size_t)2 * NBUCK * CURPAD * 4);

    MegaArgs margs;
    margs.src_sc = ei_sc;            margs.dst_sc = ei_sc + N_EDGES;
    margs.src_fc = ei_fc;            margs.dst_fc = ei_fc + N_EDGES;
    margs.pairs_sc = pairs_sc;       margs.pairs_fc = pairs_fc;
    margs.cursor = cursor;
    margs.x = x;                     margs.xh = xh;
    margs.W0 = W0;                   margs.W1 = W1;
    margs.wfrag = wfrag;
    margs.sorted_sc = sorted_sc;     margs.sorted_fc = sorted_fc;
    margs.rowg_sc = rowg_sc;         margs.rowg_fc = rowg_fc;
    margs.b0 = b0;                   margs.b1 = b1;
    margs.Hs = Hs_;                  margs.Hf = Hf_;
    margs.Gs = Gs_;                  margs.Gf = Gf_;
    margs.Wout = Wout;               margs.bout = bout;
    margs.batch = batch;
    margs.out = (float*)d_out;

    // grid size: guaranteed-co-resident cooperative grid (256 CUs on MI355X)
    int maxBlk = 0;
    if (hipOccupancyMaxActiveBlocksPerMultiprocessor(&maxBlk, (const void*)mega_kernel,
                                                     512, 0) != hipSuccess || maxBlk < 1)
        maxBlk = 1;
    int nblocks = maxBlk * 256;
    if (nblocks > 512) nblocks = 512;

    hipMemsetAsync(cursor, 0, (size_t)2 * NBUCK * CURPAD * sizeof(int), stream);
    void* kargs[] = { (void*)&margs };
    hipLaunchCooperativeKernel((const void*)mega_kernel, dim3(nblocks), dim3(512),
                               kargs, 0, stream);
}

// Round 18
// 126.446 us; speedup vs baseline: 3.0968x; 3.0968x over previous
//
#include <hip/hip_runtime.h>
#include <hip/hip_fp16.h>

#define N_NODES 50000
#define N_EDGES 800000
#define DIM 64
#define N_GRAPH 512
#define N_CLASS 10
#define NTILES (N_NODES / 16)                 // 3125 MFMA row-tiles
#define BUCK 128                              // nodes per bucket
#define NBUCK ((N_NODES + BUCK - 1) / BUCK)   // 391
#define CAP 4096                              // edge capacity per bucket (mean ~2046)
#define NBA 128                               // bucket blocks per branch
#define EPA (N_EDGES / NBA)                   // 6250 edges per block
#define RSTRIDE (BUCK + 1)                    // 129
#define APAD 72                               // As16 row stride (halves), +8 pad
#define LGRID (((2 * NTILES + 7) / 8) * 8)    // 6256: 1D layer grid, XCD-pinned branches

typedef _Float16 f16;
typedef f16 f16x8 __attribute__((ext_vector_type(8)));
typedef float f32x4 __attribute__((ext_vector_type(4)));

// ---------------- fused prep: bucket sort + x->fp16 + W fragments ----------------
__global__ void __launch_bounds__(1024)
prep_kernel(const int* __restrict__ src_sc, const int* __restrict__ dst_sc,
            const int* __restrict__ src_fc, const int* __restrict__ dst_fc,
            unsigned int* __restrict__ pairs_sc, unsigned int* __restrict__ pairs_fc,
            int* __restrict__ cursor,
            const float* __restrict__ x, __half* __restrict__ xh,
            const float* __restrict__ W0, const float* __restrict__ W1,
            f16* __restrict__ wfrag) {
    __shared__ int hist[NBUCK];
    __shared__ int cbase[NBUCK];
    __shared__ int cnt2[NBUCK];
    const int* src; const int* dst; unsigned int* pairs; int* cur;
    if (blockIdx.y == 0) { src = src_sc; dst = dst_sc; pairs = pairs_sc; cur = cursor; }
    else                 { src = src_fc; dst = dst_fc; pairs = pairs_fc; cur = cursor + NBUCK; }
    int t = threadIdx.x;
    int gtid = (blockIdx.y * NBA + blockIdx.x) * 1024 + t;   // 0..262143

    // striped conv: 800000 float4 -> half8
    for (int i = gtid; i < N_NODES * DIM / 4; i += NBA * 2 * 1024) {
        float4 v = *(const float4*)(x + (size_t)i * 4);
        union { __half2 h2[2]; float2 f2; } u;
        u.h2[0] = __floats2half2_rn(v.x, v.y);
        u.h2[1] = __floats2half2_rn(v.z, v.w);
        *(float2*)(xh + (size_t)i * 4) = u.f2;
    }
    // striped wfrag: 4 matrices x 4096 entries
    if (gtid < 4 * 4096) {
        int mat = gtid >> 12, idx = gtid & 4095;
        const float* W = (mat & 2) ? W1 : W0;
        if (mat & 1) W += DIM * DIM;
        int ct = idx >> 10, kk = (idx >> 9) & 1, l = (idx >> 3) & 63, i = idx & 7;
        int k = kk * 32 + (l >> 4) * 8 + i;
        int col = ct * 16 + (l & 15);
        wfrag[mat * 4096 + idx] = (f16)W[k * DIM + col];
    }

    if (t < NBUCK) { hist[t] = 0; cnt2[t] = 0; }
    __syncthreads();
    int base = blockIdx.x * EPA;
    for (int e = base + t; e < base + EPA; e += 1024)
        atomicAdd(&hist[dst[e] >> 7], 1);
    __syncthreads();
    if (t < NBUCK) cbase[t] = atomicAdd(&cur[t], hist[t]);
    __syncthreads();
    for (int e = base + t; e < base + EPA; e += 1024) {
        int d = dst[e];
        int q = d >> 7;
        int idx = atomicAdd(&cnt2[q], 1) + cbase[q];
        if (idx < CAP)
            pairs[(size_t)q * CAP + idx] =
                (unsigned int)src[e] | ((unsigned int)(d & (BUCK - 1)) << 16);
    }
}

// ---------------- per-bucket LDS counting sort -> global sorted list + rows ----------
__global__ void __launch_bounds__(512)
sortb_kernel(const unsigned int* __restrict__ pairs_sc,
             const unsigned int* __restrict__ pairs_fc,
             const int* __restrict__ cursor,
             unsigned short* __restrict__ sorted_sc, unsigned short* __restrict__ sorted_fc,
             int* __restrict__ rowg_sc, int* __restrict__ rowg_fc) {
    __shared__ unsigned short slo[CAP];        // 8 KB
    __shared__ int row[BUCK + 1];
    __shared__ int cur[BUCK];
    int q = blockIdx.x;
    const unsigned int* pairs; unsigned short* sorted; int* rowg; int cnt;
    if (blockIdx.y == 0) { pairs = pairs_sc; sorted = sorted_sc; rowg = rowg_sc; cnt = cursor[q]; }
    else                 { pairs = pairs_fc; sorted = sorted_fc; rowg = rowg_fc; cnt = cursor[NBUCK + q]; }
    if (cnt > CAP) cnt = CAP;
    int t = threadIdx.x;
    if (t < BUCK) { row[t + 1] = 0; cur[t] = 0; }
    if (t == 0) row[0] = 0;
    __syncthreads();
    const unsigned int* pq = pairs + (size_t)q * CAP;
    for (int e = t; e < cnt; e += 512)
        atomicAdd(&row[(pq[e] >> 16) + 1], 1);
    __syncthreads();
    for (int off = 1; off < BUCK; off <<= 1) {      // scan row[1..BUCK]
        int v = 0;
        if (t < BUCK && (t + 1) - off >= 1) v = row[t + 1 - off];
        __syncthreads();
        if (t < BUCK) row[t + 1] += v;
        __syncthreads();
    }
    for (int e = t; e < cnt; e += 512) {
        unsigned int u = pq[e];
        int dl = u >> 16;
        int pos = row[dl] + atomicAdd(&cur[dl], 1);
        slo[pos] = (unsigned short)(u & 0xffffu);
    }
    __syncthreads();
    for (int i = t; i <= BUCK; i += 512) rowg[q * RSTRIDE + i] = row[i];
    unsigned int* so = (unsigned int*)(sorted + (size_t)q * CAP);
    const unsigned int* sl2 = (const unsigned int*)slo;
    int n2 = (cnt + 1) >> 1;
    for (int i = t; i < n2; i += 512) so[i] = sl2[i];
}

// ---------------- fused gather-aggregate + MFMA linear + relu ----------------
// 1D grid, XCD-pinned branches: slot = bid & 7; branch = slot >> 2 (sc on XCD 0-3,
// fc on 4-7 under the round-robin dispatch heuristic -- perf-only, not correctness).
// One block (256 thr = 4 waves) per 16-node tile.
__global__ void __launch_bounds__(256)
layer_kernel(const unsigned short* __restrict__ sorted_a, const int* __restrict__ rowg_a,
             const __half* __restrict__ in_a, const f16* __restrict__ wf_a,
             const float* __restrict__ bias_a, __half* __restrict__ out_a,
             const unsigned short* __restrict__ sorted_b, const int* __restrict__ rowg_b,
             const __half* __restrict__ in_b, const f16* __restrict__ wf_b,
             const float* __restrict__ bias_b, __half* __restrict__ out_b) {
    int bid = blockIdx.x;
    int slot = bid & 7;
    int br = slot >> 2;
    int tile = (bid >> 3) * 4 + (slot & 3);
    if (tile >= NTILES) return;

    const unsigned short* sorted; const int* rowg; const f16* in;
    const f16* wf; const float* bias; f16* out;
    if (br == 0) { sorted = sorted_a; rowg = rowg_a; in = (const f16*)in_a; wf = wf_a; bias = bias_a; out = (f16*)out_a; }
    else         { sorted = sorted_b; rowg = rowg_b; in = (const f16*)in_b; wf = wf_b; bias = bias_b; out = (f16*)out_b; }

    __shared__ f16 As16[16][APAD];
    int t = threadIdx.x;
    int w = t >> 6, lane = t & 63;
    int nbase = tile * 16;
    int q = nbase >> 7;
    const unsigned short* slo = sorted + (size_t)q * CAP;
    const int* rr = rowg + q * RSTRIDE;

    // ---- phase 1: gather 4 nodes per wave ----
    int eg = lane >> 3, c8 = (lane & 7) << 3;
#pragma unroll
    for (int i = 0; i < 4; ++i) {
        int nl = w * 4 + i;                    // node within tile
        int dl = (nbase & (BUCK - 1)) + nl;    // node within bucket
        int beg = rr[dl], end = rr[dl + 1];
        float iv = 1.0f / fmaxf((float)(end - beg), 1.0f);
        float acc[8] = {0.f, 0.f, 0.f, 0.f, 0.f, 0.f, 0.f, 0.f};
        int k = beg;
        for (; k + 16 <= end; k += 16) {
            int s0 = slo[k + eg];
            int s1 = slo[k + 8 + eg];
            f16x8 v0 = *(const f16x8*)(in + (size_t)s0 * DIM + c8);
            f16x8 v1 = *(const f16x8*)(in + (size_t)s1 * DIM + c8);
#pragma unroll
            for (int m = 0; m < 8; ++m) acc[m] += (float)v0[m] + (float)v1[m];
        }
        if (k + 8 <= end) {
            f16x8 v0 = *(const f16x8*)(in + (size_t)slo[k + eg] * DIM + c8);
#pragma unroll
            for (int m = 0; m < 8; ++m) acc[m] += (float)v0[m];
            k += 8;
        }
        if (k + eg < end) {
            f16x8 v0 = *(const f16x8*)(in + (size_t)slo[k + eg] * DIM + c8);
#pragma unroll
            for (int m = 0; m < 8; ++m) acc[m] += (float)v0[m];
        }
#pragma unroll
        for (int m = 0; m < 8; ++m) {
            acc[m] += __shfl_xor(acc[m], 8, 64);
            acc[m] += __shfl_xor(acc[m], 16, 64);
            acc[m] += __shfl_xor(acc[m], 32, 64);
        }
        if (eg == 0) {
            f16x8 r;
#pragma unroll
            for (int m = 0; m < 8; ++m) r[m] = (f16)(acc[m] * iv);
            *(f16x8*)&As16[nl][c8] = r;
        }
    }
    __syncthreads();

    // ---- phase 2: MFMA, wave w owns output quadrant ct=w ----
    int g = lane >> 4, c = lane & 15;
    f16x8 a0 = *(const f16x8*)&As16[c][8 * g];
    f16x8 a1 = *(const f16x8*)&As16[c][32 + 8 * g];
    f16x8 b0 = *(const f16x8*)(wf + ((w * 2 + 0) * 64 + lane) * 8);
    f16x8 b1 = *(const f16x8*)(wf + ((w * 2 + 1) * 64 + lane) * 8);
    f32x4 acc = {0.f, 0.f, 0.f, 0.f};
    acc = __builtin_amdgcn_mfma_f32_16x16x32_f16(a0, b0, acc, 0, 0, 0);
    acc = __builtin_amdgcn_mfma_f32_16x16x32_f16(a1, b1, acc, 0, 0, 0);
    float bs = bias[w * 16 + c];
#pragma unroll
    for (int i = 0; i < 4; ++i) {
        float v = fmaxf(acc[i] + bs, 0.0f);
        out[((size_t)nbase + 4 * g + i) * DIM + w * 16 + c] = (f16)v;
    }
}

// ---------------- per-graph projection ----------------
__global__ void graph_proj_kernel(const __half* __restrict__ x0, const __half* __restrict__ x1,
                                  const float* __restrict__ Wout, const float* __restrict__ bout,
                                  const int* __restrict__ batch, float* __restrict__ out) {
    int g = blockIdx.x;
    __shared__ int bounds[2];
    __shared__ float hs[4][DIM];
    int t = threadIdx.x;
    if (t < 2) {
        int target = g + t;
        int lo = 0, hi = N_NODES;
        while (lo < hi) { int mid = (lo + hi) >> 1; if (batch[mid] < target) lo = mid + 1; else hi = mid; }
        bounds[t] = lo;
    }
    __syncthreads();
    int beg = bounds[0], end = bounds[1];
    int w = t >> 6, j = t & 63;
    float s = 0.0f;
    for (int n = beg + w; n < end; n += 4)
        s += __half2float(x0[(size_t)n * DIM + j]) + __half2float(x1[(size_t)n * DIM + j]);
    hs[w][j] = s;
    __syncthreads();
    if (t < DIM) hs[0][t] = (hs[0][t] + hs[1][t] + hs[2][t] + hs[3][t]) * 0.5f;
    __syncthreads();
    if (t < N_CLASS) {
        int cnt = end - beg;
        float acc = 0.0f;
#pragma unroll
        for (int d = 0; d < DIM; ++d) acc += hs[0][d] * Wout[d * N_CLASS + t];
        out[g * N_CLASS + t] = (cnt > 0) ? (acc / (float)cnt + bout[t]) : 0.0f;
    }
}

extern "C" void kernel_launch(void* const* d_in, const int* in_sizes, int n_in,
                              void* d_out, int out_size, void* d_ws, size_t ws_size,
                              hipStream_t stream) {
    const float* x    = (const float*)d_in[0];
    const float* W0   = (const float*)d_in[1];
    const float* b0   = (const float*)d_in[2];
    const float* W1   = (const float*)d_in[3];
    const float* b1   = (const float*)d_in[4];
    const float* Wout = (const float*)d_in[5];
    const float* bout = (const float*)d_in[6];
    const int* ei_sc  = (const int*)d_in[7];
    const int* ei_fc  = (const int*)d_in[8];
    const int* batch  = (const int*)d_in[9];

    const int* src_sc = ei_sc;
    const int* dst_sc = ei_sc + N_EDGES;
    const int* src_fc = ei_fc;
    const int* dst_fc = ei_fc + N_EDGES;

    // ---- workspace layout (byte-based) ----
    char* ws = (char*)d_ws;
    size_t off = 0;
    auto alloc = [&](size_t bytes) { void* p = ws + off; off += (bytes + 15) & ~size_t(15); return p; };
    __half* xh   = (__half*)alloc((size_t)N_NODES * DIM * 2);
    __half* Hs_  = (__half*)alloc((size_t)N_NODES * DIM * 2);   // layer-0 out sc
    __half* Hf_  = (__half*)alloc((size_t)N_NODES * DIM * 2);   // layer-0 out fc
    __half* Gs_  = (__half*)alloc((size_t)N_NODES * DIM * 2);   // layer-1 out sc
    __half* Gf_  = (__half*)alloc((size_t)N_NODES * DIM * 2);   // layer-1 out fc
    f16*   wfrag = (f16*)alloc(4 * 4096 * 2);
    unsigned int* pairs_sc = (unsigned int*)alloc((size_t)NBUCK * CAP * 4);  // 6.4 MB
    unsigned int* pairs_fc = (unsigned int*)alloc((size_t)NBUCK * CAP * 4);
    unsigned short* sorted_sc = (unsigned short*)alloc((size_t)NBUCK * CAP * 2);
    unsigned short* sorted_fc = (unsigned short*)alloc((size_t)NBUCK * CAP * 2);
    int* rowg_sc = (int*)alloc((size_t)NBUCK * RSTRIDE * 4);
    int* rowg_fc = (int*)alloc((size_t)NBUCK * RSTRIDE * 4);
    int* cursor  = (int*)alloc(2 * NBUCK * 4);

    // ---- 6-dispatch pipeline ----
    hipMemsetAsync(cursor, 0, 2 * NBUCK * sizeof(int), stream);
    prep_kernel<<<dim3(NBA, 2), 1024, 0, stream>>>(
        src_sc, dst_sc, src_fc, dst_fc, pairs_sc, pairs_fc, cursor,
        x, xh, W0, W1, wfrag);
    sortb_kernel<<<dim3(NBUCK, 2), 512, 0, stream>>>(
        pairs_sc, pairs_fc, cursor, sorted_sc, sorted_fc, rowg_sc, rowg_fc);

    layer_kernel<<<LGRID, 256, 0, stream>>>(
        sorted_sc, rowg_sc, xh, wfrag + 0 * 4096, b0, Hs_,
        sorted_fc, rowg_fc, xh, wfrag + 2 * 4096, b1, Hf_);
    layer_kernel<<<LGRID, 256, 0, stream>>>(
        sorted_sc, rowg_sc, Hs_, wfrag + 1 * 4096, b0 + DIM, Gs_,
        sorted_fc, rowg_fc, Hf_, wfrag + 3 * 4096, b1 + DIM, Gf_);

    graph_proj_kernel<<<N_GRAPH, 256, 0, stream>>>(Gs_, Gf_, Wout, bout, batch,
                                                   (float*)d_out);
}